// Round 1
// baseline (9568.871 us; speedup 1.0000x reference)
//
#include <hip/hip_runtime.h>

#define T_LEN 8192
#define HH 128
#define G4 512
#define E_DIM 50
#define KT 23
#define START_T 21
#define STOP_T 22
#define NEGV -10000.0f

__device__ __forceinline__ float rl(float v, int lane) {
  return __int_as_float(__builtin_amdgcn_readlane(__float_as_int(v), lane));
}

// ---------------------------------------------------------------------------
// K1: pre[t][j] = Wih[row(j)] . x_t + bih + bhh   (row permuted for k_lstm)
// row(j) = ((j&3)<<7) | (j>>2)  -> lane quads hold i,f,g,o of one hidden dim
// grid: 512 blocks (dir*256 + chunk of 32 t), 512 threads
// ---------------------------------------------------------------------------
__global__ __launch_bounds__(512) void k_pre(
    const int* __restrict__ sentence, const float* __restrict__ embed,
    const float* __restrict__ Wih_f, const float* __restrict__ bih_f, const float* __restrict__ bhh_f,
    const float* __restrict__ Wih_b, const float* __restrict__ bih_b, const float* __restrict__ bhh_b,
    float* __restrict__ pre_f, float* __restrict__ pre_b)
{
  const int dir = blockIdx.x >> 8;
  const int t0 = (blockIdx.x & 255) * 32;
  const float* __restrict__ Wih = dir ? Wih_b : Wih_f;
  const float* __restrict__ bi  = dir ? bih_b : bih_f;
  const float* __restrict__ bh  = dir ? bhh_b : bhh_f;
  float* __restrict__ pre = dir ? pre_b : pre_f;
  const int j = threadIdx.x;
  const int r = ((j & 3) << 7) | (j >> 2);
  float w[E_DIM];
  {
    const float2* w2 = (const float2*)(Wih + r * E_DIM);
#pragma unroll
    for (int q = 0; q < 25; ++q) { float2 v = w2[q]; w[2*q] = v.x; w[2*q+1] = v.y; }
  }
  const float bias = bi[r] + bh[r];
  __shared__ float xs[32][E_DIM];
  __shared__ int sidx[32];
  if (j < 32) sidx[j] = sentence[t0 + j];
  __syncthreads();
  for (int i = j; i < 32 * E_DIM; i += 512) {
    int tl = i / E_DIM;
    int e = i - tl * E_DIM;
    xs[tl][e] = embed[sidx[tl] * E_DIM + e];
  }
  __syncthreads();
  for (int tl = 0; tl < 32; ++tl) {
    float a0 = bias, a1 = 0.f;
#pragma unroll
    for (int e = 0; e < E_DIM; e += 2) {
      a0 += w[e]     * xs[tl][e];
      a1 += w[e + 1] * xs[tl][e + 1];
    }
    pre[(t0 + tl) * G4 + j] = a0 + a1;
  }
}

// ---------------------------------------------------------------------------
// K2: the serial LSTM. grid=2 (dir), 512 threads; thread j owns Whh row
// ((j&3)<<7)|(j>>2) in 128 VGPRs. h broadcast via uniform ds_read_b128.
// Quad lanes hold i,f,g,o of one hidden dim -> width-4 shuffles, 1 barrier/step.
// ---------------------------------------------------------------------------
__global__ __launch_bounds__(512, 2) void k_lstm(
    const float* __restrict__ Whh_f, const float* __restrict__ Whh_b,
    const float* __restrict__ h0, const float* __restrict__ c0,
    const float* __restrict__ pre_f, const float* __restrict__ pre_b,
    float* __restrict__ hcat)
{
  const int dir = blockIdx.x;
  const float* __restrict__ Whh = dir ? Whh_b : Whh_f;
  const float* __restrict__ pre = dir ? pre_b : pre_f;
  const int j = threadIdx.x;
  const int g = j & 3;        // 0=i,1=f,2=g,3=o
  const int d = j >> 2;       // hidden dim
  const int r = (g << 7) | d; // Whh row
  float w[128];
  {
    const float4* w4 = (const float4*)(Whh + r * 128);
#pragma unroll
    for (int q = 0; q < 32; ++q) {
      float4 v = w4[q];
      w[4*q+0] = v.x; w[4*q+1] = v.y; w[4*q+2] = v.z; w[4*q+3] = v.w;
    }
  }
  __shared__ float hbuf[2][HH];
  float c = c0[dir * HH + d];
  if (g == 0) hbuf[0][d] = h0[dir * HH + d];
  __syncthreads();
  float pcur = pre[(dir ? (T_LEN - 1) : 0) * G4 + j];
  for (int s = 0; s < T_LEN; ++s) {
    const int t = dir ? (T_LEN - 1 - s) : s;
    const int sn = (s + 1 < T_LEN) ? (s + 1) : s;
    const int tn = dir ? (T_LEN - 1 - sn) : sn;
    const float pnext = pre[tn * G4 + j];   // prefetch 1 step ahead (hidden by dot)
    const float4* h4 = (const float4*)hbuf[s & 1];
    float a0 = 0.f, a1 = 0.f, a2 = 0.f, a3 = 0.f;
#pragma unroll
    for (int q = 0; q < 32; ++q) {
      float4 hv = h4[q];
      a0 += w[4*q+0] * hv.x;
      a1 += w[4*q+1] * hv.y;
      a2 += w[4*q+2] * hv.z;
      a3 += w[4*q+3] * hv.w;
    }
    const float acc = ((a0 + a1) + (a2 + a3)) + pcur;
    pcur = pnext;
    // sigmoid for i,f,o; tanh for g (tanh(x)=2*sigmoid(2x)-1), saturation-safe
    const float sc = (g == 2) ? 2.0f : 1.0f;
    const float ev = __expf(-sc * acc);
    const float sg = 1.0f / (1.0f + ev);
    const float act = (g == 2) ? (2.0f * sg - 1.0f) : sg;
    const float iv = __shfl(act, 0, 4);
    const float fv = __shfl(act, 1, 4);
    const float gv = __shfl(act, 2, 4);
    const float ovv = __shfl(act, 3, 4);
    c = fv * c + iv * gv;                    // replicated per quad (deterministic)
    const float e2 = __expf(-2.0f * c);
    const float th = 2.0f / (1.0f + e2) - 1.0f;
    const float h = ovv * th;
    if (g == 0) {
      hbuf[(s + 1) & 1][d] = h;              // double-buffer: no WAR barrier needed
      hcat[t * (2 * HH) + dir * HH + d] = h;
    }
    __syncthreads();
  }
}

// ---------------------------------------------------------------------------
// K3: feats[t][k] = W_out[k] . hcat[t] + b_out[k].  grid 256 x 256thr.
// ---------------------------------------------------------------------------
__global__ __launch_bounds__(256) void k_feats(
    const float* __restrict__ hcat, const float* __restrict__ Wout,
    const float* __restrict__ bout, float* __restrict__ feats)
{
  const int t0 = blockIdx.x * 32;
  __shared__ float hsh[32 * 257];   // +1 pad -> conflict-free
  __shared__ float wsh[KT * 256];
  __shared__ float bsh[KT];
  const int tid = threadIdx.x;
  for (int i = tid; i < 32 * 256; i += 256) {
    int tl = i >> 8, dd = i & 255;
    hsh[tl * 257 + dd] = hcat[(t0 + tl) * 256 + dd];
  }
  for (int i = tid; i < KT * 256; i += 256) wsh[i] = Wout[i];
  if (tid < KT) bsh[tid] = bout[tid];
  __syncthreads();
  for (int idx = tid; idx < 32 * KT; idx += 256) {
    int tl = idx & 31, k = idx >> 5;
    float a0 = bsh[k], a1 = 0.f, a2 = 0.f, a3 = 0.f;
#pragma unroll 8
    for (int dd = 0; dd < 256; dd += 4) {
      a0 += hsh[tl * 257 + dd + 0] * wsh[k * 256 + dd + 0];
      a1 += hsh[tl * 257 + dd + 1] * wsh[k * 256 + dd + 1];
      a2 += hsh[tl * 257 + dd + 2] * wsh[k * 256 + dd + 2];
      a3 += hsh[tl * 257 + dd + 3] * wsh[k * 256 + dd + 3];
    }
    feats[(t0 + tl) * KT + k] = ((a0 + a1) + (a2 + a3));
  }
}

// ---------------------------------------------------------------------------
// K4: sequential Viterbi forward. 1 wave; lane j = next-tag. fv broadcast via
// v_readlane (no LDS in the loop). First-max tie semantics == jnp.argmax.
// Stores bptr bytes; writes score and best_last.
// ---------------------------------------------------------------------------
__global__ __launch_bounds__(64) void k_vit_fwd(
    const float* __restrict__ feats, const float* __restrict__ trans,
    unsigned char* __restrict__ bptr, float* __restrict__ out, int* __restrict__ misc)
{
  const int j = threadIdx.x;
  float trow[KT];
#pragma unroll
  for (int i = 0; i < KT; ++i)
    trow[i] = (j < KT) ? ((j == START_T || i == STOP_T) ? NEGV : trans[j * KT + i]) : NEGV;
  float fvn = (j == START_T) ? 0.0f : NEGV;
  float pf[8];
#pragma unroll
  for (int q = 0; q < 8; ++q) pf[q] = (j < KT) ? feats[q * KT + j] : 0.0f;
  for (int tb = 0; tb < T_LEN; tb += 8) {
#pragma unroll
    for (int q = 0; q < 8; ++q) {
      const int t = tb + q;
      float fvv[KT];
#pragma unroll
      for (int i = 0; i < KT; ++i) fvv[i] = rl(fvn, i);
      // pairs stage (tie keeps even=lower index), then linear over ascending
      // winner indices with strict > : exactly first-max like jnp.argmax.
      float pv[12]; int pi2[12];
#pragma unroll
      for (int k = 0; k < 11; ++k) {
        float c0 = fvv[2*k]     + trow[2*k];
        float c1 = fvv[2*k + 1] + trow[2*k + 1];
        bool tk = c1 > c0;
        pv[k]  = tk ? c1 : c0;
        pi2[k] = tk ? (2*k + 1) : (2*k);
      }
      pv[11] = fvv[22] + trow[22]; pi2[11] = 22;
      float best = pv[0]; int bi = pi2[0];
#pragma unroll
      for (int k = 1; k < 12; ++k)
        if (pv[k] > best) { best = pv[k]; bi = pi2[k]; }
      const float nf = best + pf[q];
      const int tpf = t + 8;
      pf[q] = (j < KT && tpf < T_LEN) ? feats[tpf * KT + j] : 0.0f;
      if (j < KT) bptr[t * KT + j] = (unsigned char)bi;
      fvn = nf;
    }
  }
  // terminal: fv + trans_c[STOP]; first-max argmax via tie-aware butterfly
  const float trS = (j < KT) ? ((j == STOP_T) ? NEGV : trans[STOP_T * KT + j]) : 0.0f;
  float term = (j < KT) ? (fvn + trS) : -3.0e38f;
  int idx = (j < KT) ? j : 63;
#pragma unroll
  for (int off = 16; off >= 1; off >>= 1) {
    float ovl = __shfl_xor(term, off);
    int oi = __shfl_xor(idx, off);
    if (ovl > term || (ovl == term && oi < idx)) { term = ovl; idx = oi; }
  }
  if (j == 0) { out[0] = term; misc[0] = idx; }
}

// ---------------------------------------------------------------------------
// K5: compose 32-step backpointer maps per chunk (parallel). maps[c][x] =
// tag at time lo-1 given tag x at time hi.
// ---------------------------------------------------------------------------
__global__ __launch_bounds__(64) void k_compose(
    const unsigned char* __restrict__ bptr, unsigned char* __restrict__ maps)
{
  const int c = blockIdx.x;
  const int lo = c * 32;
  __shared__ unsigned char rows[32 * 24];
  const int tid = threadIdx.x;
  for (int i = tid; i < 32 * KT; i += 64) {
    int tl = i / KT, e = i - tl * KT;
    rows[tl * 24 + e] = bptr[(lo + tl) * KT + e];
  }
  __syncthreads();
  if (tid < KT) {
    int x = tid;
    for (int tl = 31; tl >= 0; --tl) x = rows[tl * 24 + x];
    maps[c * KT + tid] = (unsigned char)x;
  }
}

// K6: sequential scan over 256 chunk maps -> tag at each chunk's hi boundary.
__global__ __launch_bounds__(64) void k_backscan(
    const unsigned char* __restrict__ maps, const int* __restrict__ misc,
    int* __restrict__ btags)
{
  __shared__ unsigned char msh[256 * KT];
  const int tid = threadIdx.x;
  for (int i = tid; i < 256 * KT; i += 64) msh[i] = maps[i];
  __syncthreads();
  if (tid == 0) {
    int e = misc[0];                 // best_last = tag at t = T-1 (hi of chunk 255)
    for (int c = 255; c >= 0; --c) { btags[c] = e; e = msh[c * KT + e]; }
  }
}

// K7: evaluate interior path per chunk (parallel), write tags as floats.
__global__ __launch_bounds__(64) void k_backeval(
    const unsigned char* __restrict__ bptr, const int* __restrict__ btags,
    float* __restrict__ out)
{
  const int c = blockIdx.x;
  const int lo = c * 32;
  __shared__ unsigned char rows[32 * 24];
  __shared__ int tags[32];
  const int tid = threadIdx.x;
  for (int i = tid; i < 32 * KT; i += 64) {
    int tl = i / KT, e = i - tl * KT;
    rows[tl * 24 + e] = bptr[(lo + tl) * KT + e];
  }
  __syncthreads();
  if (tid == 0) {
    int tg = btags[c];               // tag at time hi = lo+31
    tags[31] = tg;
    for (int tl = 31; tl >= 1; --tl) { tg = rows[tl * 24 + tg]; tags[tl - 1] = tg; }
  }
  __syncthreads();
  if (tid < 32) out[1 + lo + tid] = (float)tags[tid];
}

// ---------------------------------------------------------------------------
extern "C" void kernel_launch(void* const* d_in, const int* in_sizes, int n_in,
                              void* d_out, int out_size, void* d_ws, size_t ws_size,
                              hipStream_t stream) {
  const int*   sentence = (const int*)d_in[0];
  const float* embed    = (const float*)d_in[1];
  const float* Wih_f    = (const float*)d_in[2];
  const float* Whh_f    = (const float*)d_in[3];
  const float* bih_f    = (const float*)d_in[4];
  const float* bhh_f    = (const float*)d_in[5];
  const float* Wih_b    = (const float*)d_in[6];
  const float* Whh_b    = (const float*)d_in[7];
  const float* bih_b    = (const float*)d_in[8];
  const float* bhh_b    = (const float*)d_in[9];
  const float* Wout     = (const float*)d_in[10];
  const float* bout     = (const float*)d_in[11];
  const float* trans    = (const float*)d_in[12];
  const float* h0       = (const float*)d_in[13];
  const float* c0       = (const float*)d_in[14];
  float* out = (float*)d_out;

  float* ws = (float*)d_ws;
  float* pre_f = ws;                               // [T][512]
  float* pre_b = pre_f + (size_t)T_LEN * G4;       // [T][512]
  float* hcat  = pre_b + (size_t)T_LEN * G4;       // [T][256]
  float* feats = hcat + (size_t)T_LEN * 2 * HH;    // [T][23]
  unsigned char* bptr = (unsigned char*)(feats + (size_t)T_LEN * KT); // [T][23] bytes
  unsigned char* maps = bptr + (size_t)T_LEN * KT; // [256][23] bytes
  int* btags = (int*)(maps + 256 * KT + 0);        // 42,891,008 bytes in: 4-aligned
  int* misc  = btags + 256;

  k_pre<<<512, 512, 0, stream>>>(sentence, embed, Wih_f, bih_f, bhh_f,
                                 Wih_b, bih_b, bhh_b, pre_f, pre_b);
  k_lstm<<<2, 512, 0, stream>>>(Whh_f, Whh_b, h0, c0, pre_f, pre_b, hcat);
  k_feats<<<256, 256, 0, stream>>>(hcat, Wout, bout, feats);
  k_vit_fwd<<<1, 64, 0, stream>>>(feats, trans, bptr, out, misc);
  k_compose<<<256, 64, 0, stream>>>(bptr, maps);
  k_backscan<<<1, 64, 0, stream>>>(maps, misc, btags);
  k_backeval<<<256, 64, 0, stream>>>(bptr, btags, out);
}